// Round 1
// baseline (2771.832 us; speedup 1.0000x reference)
//
#include <hip/hip_runtime.h>
#include <hip/hip_bf16.h>
#include <cstdint>

// Problem constants
constexpr int kB = 512;      // batch
constexpr int kT = 80;       // encoder seq len
constexpr int kC = 512;      // in_channels
constexpr int kH = 256;      // hidden
constexpr int kV = 6625;     // classes
constexpr int kGIN = kC + kV; // 7137, gru_wih leading dim

typedef __attribute__((ext_vector_type(8))) short short8;
typedef __attribute__((ext_vector_type(4))) float floatx4;

__device__ __forceinline__ float fast_tanh(float x) {
  float e = __expf(2.f * x);
  return 1.f - 2.f / (e + 1.f);
}
__device__ __forceinline__ float fast_sig(float x) {
  return 1.f / (1.f + __expf(-x));
}

__device__ __forceinline__ void gld_lds16(const void* g, void* l) {
  __builtin_amdgcn_global_load_lds(
      (const __attribute__((address_space(1))) void*)(uintptr_t)g,
      (__attribute__((address_space(3))) void*)(uintptr_t)l, 16, 0, 0);
}

// ---------------------------------------------------------------------------
// fp32 -> bf16 conversion (gen_w)
// ---------------------------------------------------------------------------
__global__ __launch_bounds__(256) void cvt_bf16(const float* __restrict__ x,
                                                __hip_bfloat16* __restrict__ y,
                                                int n) {
  int i = blockIdx.x * 256 + threadIdx.x;
  if (i < n) y[i] = __float2bfloat16(x[i]);
}

// ---------------------------------------------------------------------------
// fp32 tiled GEMM: C[M,N] = A[M,K] * W[N,K]^T  (proj = inputs @ i2h_w^T)
// 64x64 tile, BK=16, 256 threads, 4x4 microtile. M=40960, N=256, K=512.
// ---------------------------------------------------------------------------
__global__ __launch_bounds__(256) void proj_gemm(
    const float* __restrict__ A, const float* __restrict__ W,
    float* __restrict__ C) {
  constexpr int lda = kC, ldw = kC, ldc = kH, K = kC;
  __shared__ __align__(16) float As[16][72];
  __shared__ __align__(16) float Ws[16][72];
  const int tid = threadIdx.x;
  const int m0 = blockIdx.x * 64;
  const int n0 = blockIdx.y * 64;
  const int lrow = tid >> 2, lkq = tid & 3;
  const int ty = tid >> 4, tx = tid & 15;
  float acc[4][4] = {};
  for (int k0 = 0; k0 < K; k0 += 16) {
    const float* ap = A + (size_t)(m0 + lrow) * lda + k0 + lkq * 4;
    float4 av = *(const float4*)ap;
    const float* wp = W + (size_t)(n0 + lrow) * ldw + k0 + lkq * 4;
    float4 wv = *(const float4*)wp;
    As[lkq * 4 + 0][lrow] = av.x;
    As[lkq * 4 + 1][lrow] = av.y;
    As[lkq * 4 + 2][lrow] = av.z;
    As[lkq * 4 + 3][lrow] = av.w;
    Ws[lkq * 4 + 0][lrow] = wv.x;
    Ws[lkq * 4 + 1][lrow] = wv.y;
    Ws[lkq * 4 + 2][lrow] = wv.z;
    Ws[lkq * 4 + 3][lrow] = wv.w;
    __syncthreads();
#pragma unroll
    for (int k = 0; k < 16; ++k) {
      float4 a = *(const float4*)&As[k][ty * 4];
      float4 w = *(const float4*)&Ws[k][tx * 4];
      acc[0][0] += a.x * w.x; acc[0][1] += a.x * w.y; acc[0][2] += a.x * w.z; acc[0][3] += a.x * w.w;
      acc[1][0] += a.y * w.x; acc[1][1] += a.y * w.y; acc[1][2] += a.y * w.z; acc[1][3] += a.y * w.w;
      acc[2][0] += a.z * w.x; acc[2][1] += a.z * w.y; acc[2][2] += a.z * w.z; acc[2][3] += a.z * w.w;
      acc[3][0] += a.w * w.x; acc[3][1] += a.w * w.y; acc[3][2] += a.w * w.z; acc[3][3] += a.w * w.w;
    }
    __syncthreads();
  }
#pragma unroll
  for (int i = 0; i < 4; ++i)
#pragma unroll
    for (int j = 0; j < 4; ++j)
      C[(size_t)(m0 + ty * 4 + i) * ldc + n0 + tx * 4 + j] = acc[i][j];
}

// ---------------------------------------------------------------------------
// Persistent fused recurrence: 256 blocks x 512 threads, each block owns
// batch rows {2b, 2b+1} for ALL 25 steps. Row-wise independence means no
// inter-block communication: hidden state lives in LDS across steps.
// Per step: phgh matvec -> attention (e/softmax/context) -> gi matvec ->
// GRU update. Weights stream from L2 (2.5 MB, XCD-L2-resident).
// ---------------------------------------------------------------------------
__global__ __launch_bounds__(512) void fused_steps(
    const float* __restrict__ inputs,    // [B,T,C]
    const float* __restrict__ proj,      // [B*T,H]
    const int*   __restrict__ targets,   // [B,S] (int32: JAX x64 disabled)
    const float* __restrict__ h2h_w, const float* __restrict__ h2h_b,
    const float* __restrict__ whh,  const float* __restrict__ bhh,
    const float* __restrict__ wih,  const float* __restrict__ bih,
    const float* __restrict__ score_w,
    __hip_bfloat16* __restrict__ hidd,   // [B*S,H]
    int S) {
  __shared__ __align__(16) float hid_s[2][kH];      // 2 KB
  __shared__ __align__(16) float phgh_s[2][1024];   // 8 KB  [ph | gh]
  __shared__ __align__(16) float ctx_s[2][kC];      // 4 KB
  __shared__ __align__(16) float gi_s[2][768];      // 6 KB
  __shared__ __align__(16) float sw_s[kH];          // 1 KB
  __shared__ float e_s[2][kT];                      // 640 B
  const int tid = threadIdx.x;
  const int r0 = blockIdx.x * 2;
  const int wave = tid >> 6, lane = tid & 63;
  const int g = tid >> 3, q = tid & 7;   // 64 groups of 8 threads

  if (tid < kH) { sw_s[tid] = score_w[tid]; hid_s[0][tid] = 0.f; }
  else          { hid_s[1][tid - kH] = 0.f; }
  __syncthreads();

  for (int s = 0; s < S; ++s) {
    // ---- phase 1: phgh[r][0:256]=ph=h@h2h^T+b, [256:1024]=gh=h@whh^T+bhh
    // 64 groups x 16 rows each; 8 lanes cover 32 floats per pass (coalesced).
#pragma unroll 2
    for (int i = 0; i < 16; ++i) {
      const int n = g + (i << 6);
      const float* wr = (n < kH) ? (h2h_w + (size_t)n * kH)
                                 : (whh + (size_t)(n - kH) * kH);
      float a0 = 0.f, a1 = 0.f;
#pragma unroll
      for (int p = 0; p < 8; ++p) {
        const int c = p * 32 + q * 4;
        float4 w4 = *(const float4*)(wr + c);
        float4 h0 = *(const float4*)(&hid_s[0][c]);
        float4 h1 = *(const float4*)(&hid_s[1][c]);
        a0 += w4.x * h0.x + w4.y * h0.y + w4.z * h0.z + w4.w * h0.w;
        a1 += w4.x * h1.x + w4.y * h1.y + w4.z * h1.z + w4.w * h1.w;
      }
      a0 += __shfl_xor(a0, 1); a0 += __shfl_xor(a0, 2); a0 += __shfl_xor(a0, 4);
      a1 += __shfl_xor(a1, 1); a1 += __shfl_xor(a1, 2); a1 += __shfl_xor(a1, 4);
      if (q == 0) {
        const float bb = (n < kH) ? h2h_b[n] : bhh[n - kH];
        phgh_s[0][n] = a0 + bb;
        phgh_s[1][n] = a1 + bb;
      }
    }
    __syncthreads();

    // ---- phase 2a: e[r][t] = sum_h tanh(proj[r,t,h]+ph[r,h])*sw[h]
    // 160 (r,t) tasks over 8 waves; one wave-pass of 256 elems per task.
    for (int tau = wave; tau < 2 * kT; tau += 8) {
      const int r = tau & 1, t = tau >> 1;
      const float* pp = proj + ((size_t)(r0 + r) * kT + t) * kH + lane * 4;
      float4 pr = *(const float4*)pp;
      float4 ph4 = *(const float4*)(&phgh_s[r][lane * 4]);
      float4 s4 = *(const float4*)(&sw_s[lane * 4]);
      float part = fast_tanh(pr.x + ph4.x) * s4.x +
                   fast_tanh(pr.y + ph4.y) * s4.y +
                   fast_tanh(pr.z + ph4.z) * s4.z +
                   fast_tanh(pr.w + ph4.w) * s4.w;
#pragma unroll
      for (int off = 32; off > 0; off >>= 1) part += __shfl_xor(part, off);
      if (lane == 0) e_s[r][t] = part;
    }
    __syncthreads();

    // ---- phase 2b: softmax over T=80 (wave r handles row r)
    if (wave < 2) {
      const int r = wave;
      float v0 = e_s[r][lane];
      float v1 = (lane < kT - 64) ? e_s[r][64 + lane] : -1e30f;
      float mx = fmaxf(v0, v1);
#pragma unroll
      for (int off = 32; off > 0; off >>= 1) mx = fmaxf(mx, __shfl_xor(mx, off));
      float x0 = __expf(v0 - mx);
      float x1 = (lane < kT - 64) ? __expf(v1 - mx) : 0.f;
      float sm = x0 + x1;
#pragma unroll
      for (int off = 32; off > 0; off >>= 1) sm += __shfl_xor(sm, off);
      float inv = 1.f / sm;
      e_s[r][lane] = x0 * inv;
      if (lane < kT - 64) e_s[r][64 + lane] = x1 * inv;
    }
    __syncthreads();

    // ---- phase 2c: context[r][c] = sum_t alpha[r][t]*inputs[r,t,c]
    {
      const float* i0 = inputs + (size_t)r0 * kT * kC + tid;
      const float* i1 = i0 + (size_t)kT * kC;
      float c0 = 0.f, c1 = 0.f;
#pragma unroll 4
      for (int t = 0; t < kT; ++t) {
        c0 += e_s[0][t] * i0[(size_t)t * kC];
        c1 += e_s[1][t] * i1[(size_t)t * kC];
      }
      ctx_s[0][tid] = c0;
      ctx_s[1][tid] = c1;
    }
    __syncthreads();

    // ---- phase 3: gi[r][n] = ctx[r]@wih[n,:C] + bih[n] + wih[n, C+tgt_r]
    // wih rows are 7137 floats (odd) -> scalar loads (row base not 16B-aligned)
    {
      const int t0 = targets[(size_t)r0 * S + s];
      const int t1 = targets[(size_t)(r0 + 1) * S + s];
#pragma unroll 2
      for (int i = 0; i < 12; ++i) {
        const int n = g + (i << 6);
        const float* wr = wih + (size_t)n * kGIN;
        float a0 = 0.f, a1 = 0.f;
#pragma unroll
        for (int p = 0; p < 16; ++p) {
          const int c = p * 32 + q * 4;
          float4 x0 = *(const float4*)(&ctx_s[0][c]);
          float4 x1 = *(const float4*)(&ctx_s[1][c]);
          float w0 = wr[c], w1 = wr[c + 1], w2 = wr[c + 2], w3 = wr[c + 3];
          a0 += w0 * x0.x + w1 * x0.y + w2 * x0.z + w3 * x0.w;
          a1 += w0 * x1.x + w1 * x1.y + w2 * x1.z + w3 * x1.w;
        }
        a0 += __shfl_xor(a0, 1); a0 += __shfl_xor(a0, 2); a0 += __shfl_xor(a0, 4);
        a1 += __shfl_xor(a1, 1); a1 += __shfl_xor(a1, 2); a1 += __shfl_xor(a1, 4);
        if (q == 0) {
          const float bb = bih[n];
          gi_s[0][n] = a0 + bb + wr[kC + t0];
          gi_s[1][n] = a1 + bb + wr[kC + t1];
        }
      }
    }
    __syncthreads();

    // ---- phase 4: GRU update (512 threads = 2 rows x 256 h)
    {
      const int r = tid >> 8, h = tid & 255;
      float i_r = gi_s[r][h];
      float i_z = gi_s[r][kH + h];
      float i_n = gi_s[r][2 * kH + h];
      float h_r = phgh_s[r][kH + h];
      float h_z = phgh_s[r][2 * kH + h];
      float h_n = phgh_s[r][3 * kH + h];
      float hv = hid_s[r][h];
      float rr = fast_sig(i_r + h_r);
      float z = fast_sig(i_z + h_z);
      float nn = fast_tanh(i_n + rr * h_n);
      float o = (1.f - z) * nn + z * hv;
      hid_s[r][h] = o;
      hidd[((size_t)(r0 + r) * S + s) * kH + h] = __float2bfloat16(o);
    }
    __syncthreads();
  }
}

// ---------------------------------------------------------------------------
// Final GEMM, bf16 MFMA: C[M,N] = A[M,K] * W[N,K]^T + bias[n]
// 128x128 tile, BK=32, 4 waves in 2x2, 16x16x32 mfma, global_load_lds x16.
// M=12800 (divides 128), N=6625 (guarded), K=256.
// ---------------------------------------------------------------------------
__global__ __launch_bounds__(256) void final_gemm(
    const __hip_bfloat16* __restrict__ A, const __hip_bfloat16* __restrict__ W,
    const float* __restrict__ bias, float* __restrict__ C, int M, int N, int K) {
  __shared__ __align__(16) short As[128 * 32];
  __shared__ __align__(16) short Ws[128 * 32];
  const int tid = threadIdx.x;
  const int wave = tid >> 6, lane = tid & 63;
  const int m0 = blockIdx.x * 128, n0 = blockIdx.y * 128;
  floatx4 acc[4][4] = {};
  const int lr = lane & 15;
  const int lkb = (lane >> 4) * 8;           // frag k offset (elements)
  const int mloc = (wave & 1) * 64;
  const int nloc = (wave >> 1) * 64;
  const int srow = wave * 16 + (lane >> 2);  // staging row within a 64-row round
  const int skq = (lane & 3) * 8;            // staging k offset (elements)
  for (int kt = 0; kt < K; kt += 32) {
#pragma unroll
    for (int r = 0; r < 2; ++r) {
      int rowA = r * 64 + srow;
      const __hip_bfloat16* ga = A + (size_t)(m0 + rowA) * K + kt + skq;
      gld_lds16(ga, (char*)As + (size_t)(r * 64 + wave * 16) * 64);
      int rowW = n0 + rowA;
      if (rowW > N - 1) rowW = N - 1;  // clamp; stores are guarded
      const __hip_bfloat16* gw = W + (size_t)rowW * K + kt + skq;
      gld_lds16(gw, (char*)Ws + (size_t)(r * 64 + wave * 16) * 64);
    }
    __syncthreads();
    short8 af[4], wf[4];
#pragma unroll
    for (int i = 0; i < 4; ++i)
      af[i] = *(const short8*)(As + (mloc + i * 16 + lr) * 32 + lkb);
#pragma unroll
    for (int j = 0; j < 4; ++j)
      wf[j] = *(const short8*)(Ws + (nloc + j * 16 + lr) * 32 + lkb);
#pragma unroll
    for (int i = 0; i < 4; ++i)
#pragma unroll
      for (int j = 0; j < 4; ++j)
        acc[i][j] = __builtin_amdgcn_mfma_f32_16x16x32_bf16(af[i], wf[j], acc[i][j], 0, 0, 0);
    __syncthreads();
  }
#pragma unroll
  for (int i = 0; i < 4; ++i) {
#pragma unroll
    for (int j = 0; j < 4; ++j) {
      int col = n0 + nloc + j * 16 + lr;
      if (col < N) {
        int rowb = m0 + mloc + i * 16 + ((lane >> 4) << 2);
        float bs = bias[col];
#pragma unroll
        for (int r = 0; r < 4; ++r)
          C[(size_t)(rowb + r) * N + col] = acc[i][j][r] + bs;
      }
    }
  }
}

// ---------------------------------------------------------------------------
extern "C" void kernel_launch(void* const* d_in, const int* in_sizes, int n_in,
                              void* d_out, int out_size, void* d_ws, size_t ws_size,
                              hipStream_t stream) {
  const float* inputs  = (const float*)d_in[0];
  const int*   targets = (const int*)d_in[1];
  // d_in[2] = batch_max_length (device scalar); S derived from out_size instead
  const float* i2h_w   = (const float*)d_in[3];
  const float* h2h_w   = (const float*)d_in[4];
  const float* h2h_b   = (const float*)d_in[5];
  const float* score_w = (const float*)d_in[6];
  const float* gru_wih = (const float*)d_in[7];
  const float* gru_whh = (const float*)d_in[8];
  const float* gru_bih = (const float*)d_in[9];
  const float* gru_bhh = (const float*)d_in[10];
  const float* gen_w   = (const float*)d_in[11];
  const float* gen_b   = (const float*)d_in[12];
  float* out = (float*)d_out;
  const int S = out_size / (kB * kV);  // 25

  // workspace carve (~52 MB total)
  char* ws = (char*)d_ws;
  size_t off = 0;
  auto alloc = [&](size_t bytes) {
    void* p = ws + off;
    off += (bytes + 255) & ~(size_t)255;
    return p;
  };
  float* proj  = (float*)alloc((size_t)kB * kT * kH * 4);       // 41.9 MB
  __hip_bfloat16* hidd = (__hip_bfloat16*)alloc((size_t)kB * S * kH * 2);
  __hip_bfloat16* gw16 = (__hip_bfloat16*)alloc((size_t)kV * kH * 2);

  cvt_bf16<<<dim3((kV * kH + 255) / 256), 256, 0, stream>>>(gen_w, gw16, kV * kH);

  // proj = inputs @ i2h_w^T   [B*T, H], K=C
  proj_gemm<<<dim3(kB * kT / 64, kH / 64), 256, 0, stream>>>(inputs, i2h_w, proj);

  // the entire 25-step recurrence: one persistent kernel, no grid syncs
  fused_steps<<<dim3(kB / 2), 512, 0, stream>>>(
      inputs, proj, targets, h2h_w, h2h_b, gru_whh, gru_bhh,
      gru_wih, gru_bih, score_w, hidd, S);

  // probs = hidd @ gen_w^T + gen_b   [B*S, V], K=H (bf16 MFMA)
  final_gemm<<<dim3(kB * S / 128, (kV + 127) / 128), 256, 0, stream>>>(
      hidd, gw16, gen_b, out, kB * S, kV, kH);
}